// Round 9
// baseline (95.984 us; speedup 1.0000x reference)
//
#include <hip/hip_runtime.h>

#define PAD 0
#define CONST_NO 10000
#define Bn 8
#define Sn 64
#define Gn 8
#define Fn 200000
#define Rn 200
#define BMAXn 3
#define KF 64
#define KR 32

#define NBLK 196
#define CHB  1024
#define BCAP 128                        // per-block hit cap (expected ~1)

// ---- workspace layout (ints) ----
#define OFF_BCNT   0                    // 196: per-probe-block hit count
#define OFF_BENT   200                  // 196*BCAP: packed (s<<18 | factidx)
#define OFF_PN     (200 + NBLK * BCAP)          // 64 : per-pred min(count,64)
#define OFF_PFIRST (OFF_PN + 64)                // 64*64: first-64 fact idx per pred

__device__ __forceinline__ bool isv(int x) { return x > CONST_NO; }

// ---------- fused: blocks [0,196) probe facts vs const-queries;
//                   blocks [196,246) collect first-64 per predicate ----------
__global__ __launch_bounds__(256) void probe_kernel(
    const int* __restrict__ goals, const int* __restrict__ facts,
    int* __restrict__ ws)
{
    const int t = threadIdx.x;
    const int lane = t & 63, wv = t >> 6;

    if (blockIdx.x < NBLK) {
        // ================= probe role =================
        __shared__ int4 qlist[512];
        __shared__ int qcnt[64], qstart[64];
        __shared__ int ebuf[BCAP];
        __shared__ int ecnt;
        const int B = blockIdx.x;

        if (t < 64) qcnt[t] = 0;
        if (t == 0) ecnt = 0;
        __syncthreads();

        // stage the 512 queries, bucketed by predicate (const-arg queries only)
        int myPos[2], myQp[2], myQv[2], myQm[2];
        #pragma unroll
        for (int k = 0; k < 2; ++k) {
            const int s = t + k * 256;
            const int* q = goals + s * (Gn * 3);
            const int qp = q[0], qa0 = q[1], qa1 = q[2];
            const bool v0 = isv(qa0), v1 = isv(qa1);
            const bool use = (qp != PAD) && !(v0 && v1);
            myQp[k] = use ? qp : -1;
            myQv[k] = (v0 ? 0 : (qa0 << 14)) | (v1 ? 0 : qa1);
            myQm[k] = (v0 ? 0 : (0x3FFF << 14)) | (v1 ? 0 : 0x3FFF);
            myPos[k] = use ? atomicAdd(&qcnt[qp], 1) : -1;
        }
        __syncthreads();
        if (t < 64) {
            const int v = qcnt[t];
            int incl = v;
            #pragma unroll
            for (int off = 1; off < 64; off <<= 1) {
                int n = __shfl_up(incl, off, 64);
                if (t >= off) incl += n;
            }
            qstart[t] = incl - v;
        }
        __syncthreads();
        #pragma unroll
        for (int k = 0; k < 2; ++k)
            if (myQp[k] >= 0)
                qlist[qstart[myQp[k]] + myPos[k]] =
                    make_int4(myQv[k], myQm[k], (t + k * 256) << 18, 0);
        __syncthreads();

        // stream this block's 1024 facts; compare against the predicate bucket
        const int f0 = B * CHB + t * 4;
        int pv[4], pk[4];
        if (f0 + 3 < Fn) {
            const int4* p4 = (const int4*)(facts + 3 * f0);
            int4 a = p4[0], b4 = p4[1], c4 = p4[2];
            pv[0] = a.x;  pk[0] = (a.y  << 14) | a.z;
            pv[1] = a.w;  pk[1] = (b4.x << 14) | b4.y;
            pv[2] = b4.z; pk[2] = (b4.w << 14) | c4.x;
            pv[3] = c4.y; pk[3] = (c4.z << 14) | c4.w;
        } else {
            #pragma unroll
            for (int u = 0; u < 4; ++u) {
                pv[u] = -1; pk[u] = 0;
                if (f0 + u < Fn) {
                    pv[u] = facts[3 * (f0 + u)];
                    pk[u] = (facts[3 * (f0 + u) + 1] << 14) | facts[3 * (f0 + u) + 2];
                }
            }
        }
        #pragma unroll
        for (int u = 0; u < 4; ++u) {
            if (pv[u] >= 0) {
                const int j0 = qstart[pv[u]], j1 = j0 + qcnt[pv[u]];
                for (int j = j0; j < j1; ++j) {
                    const int4 qq = qlist[j];
                    if (((pk[u] ^ qq.x) & qq.y) == 0) {
                        const int pos = atomicAdd(&ecnt, 1);
                        if (pos < BCAP) ebuf[pos] = qq.z | (f0 + u);
                    }
                }
            }
        }
        __syncthreads();
        const int n = (ecnt < BCAP) ? ecnt : BCAP;
        if (t == 0) ws[OFF_BCNT + B] = n;
        if (t < n) ws[OFF_BENT + B * BCAP + t] = ebuf[t];
    } else {
        // ================= first-64-per-predicate role =================
        __shared__ int wave_tot[4];
        const int p = blockIdx.x - NBLK + 1;       // predicate 1..50

        int total = 0;
        for (int base = 0; base < Fn && total < KF; base += 1024) {
            const int f0 = base + t * 4;
            unsigned mbits = 0;
            if (f0 + 3 < Fn) {
                const int4* p4 = (const int4*)(facts + 3 * f0);
                int4 a = p4[0], b4 = p4[1], c4 = p4[2];
                if (a.x  == p) mbits |= 1u;
                if (a.w  == p) mbits |= 2u;
                if (b4.z == p) mbits |= 4u;
                if (c4.y == p) mbits |= 8u;
            } else {
                #pragma unroll
                for (int u = 0; u < 4; ++u)
                    if (f0 + u < Fn && facts[3 * (f0 + u)] == p) mbits |= (1u << u);
            }
            const int c4n = __popc(mbits);

            int v = c4n;
            #pragma unroll
            for (int off = 1; off < 64; off <<= 1) {
                int n = __shfl_up(v, off, 64);
                if (lane >= off) v += n;
            }
            if (lane == 63) wave_tot[wv] = v;
            __syncthreads();
            int excl = v - c4n;
            #pragma unroll
            for (int w = 0; w < 4; ++w) if (w < wv) excl += wave_tot[w];
            const int ctot = wave_tot[0] + wave_tot[1] + wave_tot[2] + wave_tot[3];

            int pos = total + excl;
            #pragma unroll
            for (int u = 0; u < 4; ++u) {
                if (mbits & (1u << u)) {
                    if (pos < KF) ws[OFF_PFIRST + p * 64 + pos] = f0 + u;
                    pos++;
                }
            }
            total += ctot;
            __syncthreads();
        }
        if (t == 0) ws[OFF_PN + p] = (total < KF) ? total : KF;
    }
}

// ---------- finalize + select: one block per batch ----------
__global__ __launch_bounds__(256) void finalize_kernel(
    const int* __restrict__ goals, const float* __restrict__ ss,
    const int* __restrict__ facts, const float* __restrict__ fsc,
    const int* __restrict__ heads, const int* __restrict__ bodies,
    const int* __restrict__ rlens, const float* __restrict__ rsc,
    const int* __restrict__ ws, float* __restrict__ outp)
{
    __shared__ int sfx[Sn * 64];        // 16 KB: sorted fact idx per state
    __shared__ int E[1024];             // compacted packed entries (all batches)
    __shared__ int base[256];
    __shared__ int wtot[4];
    __shared__ int seg[4][Sn][16];      // rule segments (50 rules/wave)
    __shared__ int segc[4][Sn];
    __shared__ int hds[Rn * 3];
    __shared__ int pref[Sn + 1];
    __shared__ int nfs[Sn], vvf[Sn], qps[Sn];

    const int b = blockIdx.x, t = threadIdx.x;
    const int lane = t & 63, wv = t >> 6;

    for (int k = t; k < Rn * 3; k += 256) hds[k] = heads[k];
    segc[wv][lane] = 0;

    // prefix over the 196 probe-block counts -> entry bases
    const int myc = (t < NBLK) ? ws[OFF_BCNT + t] : 0;
    {
        int incl = myc;
        #pragma unroll
        for (int off = 1; off < 64; off <<= 1) {
            int n = __shfl_up(incl, off, 64);
            if (lane >= off) incl += n;
        }
        if (lane == 63) wtot[wv] = incl;
        __syncthreads();
        int excl = incl - myc;
        #pragma unroll
        for (int w = 0; w < 4; ++w) if (w < wv) excl += wtot[w];
        base[t] = excl;
    }
    __syncthreads();
    const int totalE0 = wtot[0] + wtot[1] + wtot[2] + wtot[3];
    const int totalE = (totalE0 < 1024) ? totalE0 : 1024;

    // compact entries into LDS (ordered by block, i.e. ascending fact region)
    if (t < NBLK) {
        for (int k = 0; k < myc; ++k) {
            const int dst = base[t] + k;
            if (dst < 1024) E[dst] = ws[OFF_BENT + t * BCAP + k];
        }
    }

    // rules: wave wv checks rules [wv*50, wv*50+50) for state s=lane
    {
        const int s = lane;
        const int* q = goals + (b * Sn + s) * (Gn * 3);
        const int qp = q[0], qa0 = q[1], qa1 = q[2];
        const bool v0 = isv(qa0), v1 = isv(qa1);
        const bool active = (qp != PAD);
        int cnt = 0;
        const int r0 = wv * 50;
        for (int r = r0; r < r0 + 50; ++r) {
            const int h0 = hds[3 * r], h1 = hds[3 * r + 1], h2 = hds[3 * r + 2];
            if (active && h0 == qp && (isv(h1) || v0 || qa0 == h1)
                                   && (isv(h2) || v1 || qa1 == h2)) {
                if (cnt < 16) seg[wv][s][cnt] = r;
                cnt++;
            }
        }
        segc[wv][s] = (cnt < 16) ? cnt : 16;
    }
    __syncthreads();

    // per-state fact lists + prefix
    if (t < Sn) {
        const int s = t;
        const int gs = b * Sn + s;              // global state id (packed key)
        const int* q = goals + gs * (Gn * 3);
        const int qp = q[0], qa0 = q[1], qa1 = q[2];
        const bool v0 = isv(qa0), v1 = isv(qa1);
        const bool active = (qp != PAD);
        const bool vv = active && v0 && v1;
        int nf = 0;
        if (vv) {
            nf = ws[OFF_PN + qp];
        } else if (active) {
            // gather my entries (unordered across blocks' ecnt races)
            for (int i = 0; i < totalE; ++i) {
                const int e = E[i];
                if ((e >> 18) == gs && nf < KF)
                    sfx[s * 64 + nf++] = e & 0x3FFFF;
            }
            // insertion sort ascending (reference order = ascending fact idx)
            for (int a = 1; a < nf; ++a) {
                const int key = sfx[s * 64 + a];
                int m = a - 1;
                while (m >= 0 && sfx[s * 64 + m] > key) {
                    sfx[s * 64 + m + 1] = sfx[s * 64 + m];
                    m--;
                }
                sfx[s * 64 + m + 1] = key;
            }
        }
        nfs[s] = nf;
        vvf[s] = vv ? 1 : 0;
        qps[s] = qp;
        int nr = segc[0][s] + segc[1][s] + segc[2][s] + segc[3][s];
        if (nr > KR) nr = KR;

        int incl = nf + nr;
        #pragma unroll
        for (int off = 1; off < 64; off <<= 1) {
            int n = __shfl_up(incl, off, 64);
            if (t >= off) incl += n;
        }
        pref[s + 1] = incl;
        if (s == 0) pref[0] = 0;
    }
    __syncthreads();
    const int total = pref[Sn];

    // emit goals: 64 slots x 8 positions = 512 items, 2 per thread
    for (int item = t; item < Sn * Gn; item += 256) {
        const int i = item >> 3, g = item & 7;
        int trip[3] = {PAD, PAD, PAD};
        if (i < total) {
            int lo = 0, hi = Sn - 1;
            while (lo < hi) {
                const int mid = (lo + hi) >> 1;
                if (pref[mid + 1] <= i) lo = mid + 1; else hi = mid;
            }
            const int s = lo, j = i - pref[s];
            const int* q = goals + (b * Sn + s) * (Gn * 3);
            const int qa0 = q[1], qa1 = q[2];
            if (j < nfs[s]) {
                const int fi = vvf[s] ? ws[OFF_PFIRST + qps[s] * 64 + j]
                                      : sfx[s * 64 + j];
                const int f1 = facts[3 * fi + 1], f2 = facts[3 * fi + 2];
                if (g >= 1) {
                    #pragma unroll
                    for (int c = 0; c < 3; ++c) {
                        int x = q[g * 3 + c];
                        if (isv(qa0) && x == qa0) x = f1;
                        else if (isv(qa1) && x == qa1) x = f2;
                        trip[c] = x;
                    }
                }
            } else {
                int jr = j - nfs[s];
                int wz = 0;
                while (jr >= segc[wz][s]) { jr -= segc[wz][s]; wz++; }
                const int ri = seg[wz][s][jr];
                const int h1 = hds[3 * ri + 1], h2 = hds[3 * ri + 2];
                const int len = rlens[ri];
                if (g < BMAXn) {
                    if (g < len) {
                        #pragma unroll
                        for (int c = 0; c < 3; ++c) {
                            int x = bodies[(ri * BMAXn + g) * 3 + c];
                            if (isv(h1) && x == h1) x = qa0;
                            if (isv(h2) && x == h2) x = qa1;
                            trip[c] = x;
                        }
                    }
                } else {
                    trip[0] = q[(g - 2) * 3 + 0];
                    trip[1] = q[(g - 2) * 3 + 1];
                    trip[2] = q[(g - 2) * 3 + 2];
                }
            }
        }
        float* o = outp + ((b * Sn + i) * Gn + g) * 3;
        o[0] = (float)trip[0];
        o[1] = (float)trip[1];
        o[2] = (float)trip[2];
    }

    // scores
    if (t < Sn) {
        const int i = t;
        float sc = 0.f;
        if (i < total) {
            int lo = 0, hi = Sn - 1;
            while (lo < hi) {
                const int mid = (lo + hi) >> 1;
                if (pref[mid + 1] <= i) lo = mid + 1; else hi = mid;
            }
            const int s = lo, j = i - pref[s];
            const float stt = ss[b * Sn + s];
            if (j < nfs[s]) {
                const int fi = vvf[s] ? ws[OFF_PFIRST + qps[s] * 64 + j]
                                      : sfx[s * 64 + j];
                sc = stt * fsc[fi];
            } else {
                int jr = j - nfs[s];
                int wz = 0;
                while (jr >= segc[wz][s]) { jr -= segc[wz][s]; wz++; }
                sc = stt * rsc[seg[wz][s][jr]];
            }
        }
        outp[Bn * Sn * Gn * 3 + b * Sn + t] = sc;
    }
}

extern "C" void kernel_launch(void* const* d_in, const int* in_sizes, int n_in,
                              void* d_out, int out_size, void* d_ws, size_t ws_size,
                              hipStream_t stream) {
    const int*   goals  = (const int*)  d_in[0];
    const float* ss     = (const float*)d_in[1];
    const int*   facts  = (const int*)  d_in[2];
    const float* fsc    = (const float*)d_in[3];
    const int*   heads  = (const int*)  d_in[4];
    const int*   bodies = (const int*)  d_in[5];
    const int*   rlens  = (const int*)  d_in[6];
    const float* rsc    = (const float*)d_in[7];
    int*   ws   = (int*)d_ws;
    float* outp = (float*)d_out;

    probe_kernel   <<<NBLK + 50, 256, 0, stream>>>(goals, facts, ws);
    finalize_kernel<<<Bn,        256, 0, stream>>>(goals, ss, facts, fsc, heads,
                                                   bodies, rlens, rsc, ws, outp);
}

// Round 10
// 91.394 us; speedup vs baseline: 1.0502x; 1.0502x over previous
//
#include <hip/hip_runtime.h>

#define PAD 0
#define CONST_NO 10000
#define Bn 8
#define Sn 64
#define Gn 8
#define Fn 200000
#define Rn 200
#define BMAXn 3
#define KF 64
#define KR 32

#define NBLK 196
#define CHB  1024
#define BCAP 128                        // per-block hit cap (expected ~1)

// ---- workspace layout (ints) ----
#define OFF_BCNT   0                    // 196: per-probe-block hit count
#define OFF_BENT   200                  // 196*BCAP: packed (s<<18 | factidx)
#define OFF_PN     (200 + NBLK * BCAP)          // 64 : per-pred min(count,64)
#define OFF_PFIRST (OFF_PN + 64)                // 64*64: first-64 fact idx per pred

__device__ __forceinline__ bool isv(int x) { return x > CONST_NO; }

// ---------- fused: blocks [0,196) probe facts vs const-queries;
//                   blocks [196,246) collect first-64 per predicate ----------
__global__ __launch_bounds__(256) void probe_kernel(
    const int* __restrict__ goals, const int* __restrict__ facts,
    int* __restrict__ ws)
{
    const int t = threadIdx.x;
    const int lane = t & 63, wv = t >> 6;

    if (blockIdx.x < NBLK) {
        // ================= probe role =================
        __shared__ int4 qlist[512];
        __shared__ int qcnt[64], qstart[64];
        __shared__ int ebuf[BCAP];
        __shared__ int ecnt;
        const int B = blockIdx.x;

        if (t < 64) qcnt[t] = 0;
        if (t == 0) ecnt = 0;
        __syncthreads();

        // stage the 512 queries, bucketed by predicate (const-arg queries only)
        int myPos[2], myQp[2], myQv[2], myQm[2];
        #pragma unroll
        for (int k = 0; k < 2; ++k) {
            const int s = t + k * 256;
            const int* q = goals + s * (Gn * 3);
            const int qp = q[0], qa0 = q[1], qa1 = q[2];
            const bool v0 = isv(qa0), v1 = isv(qa1);
            const bool use = (qp != PAD) && !(v0 && v1);
            myQp[k] = use ? qp : -1;
            myQv[k] = (v0 ? 0 : (qa0 << 14)) | (v1 ? 0 : qa1);
            myQm[k] = (v0 ? 0 : (0x3FFF << 14)) | (v1 ? 0 : 0x3FFF);
            myPos[k] = use ? atomicAdd(&qcnt[qp], 1) : -1;
        }
        __syncthreads();
        if (t < 64) {
            const int v = qcnt[t];
            int incl = v;
            #pragma unroll
            for (int off = 1; off < 64; off <<= 1) {
                int n = __shfl_up(incl, off, 64);
                if (t >= off) incl += n;
            }
            qstart[t] = incl - v;
        }
        __syncthreads();
        #pragma unroll
        for (int k = 0; k < 2; ++k)
            if (myQp[k] >= 0)
                qlist[qstart[myQp[k]] + myPos[k]] =
                    make_int4(myQv[k], myQm[k], (t + k * 256) << 18, 0);
        __syncthreads();

        // stream this block's 1024 facts; compare against the predicate bucket
        const int f0 = B * CHB + t * 4;
        int pv[4], pk[4];
        if (f0 + 3 < Fn) {
            const int4* p4 = (const int4*)(facts + 3 * f0);
            int4 a = p4[0], b4 = p4[1], c4 = p4[2];
            pv[0] = a.x;  pk[0] = (a.y  << 14) | a.z;
            pv[1] = a.w;  pk[1] = (b4.x << 14) | b4.y;
            pv[2] = b4.z; pk[2] = (b4.w << 14) | c4.x;
            pv[3] = c4.y; pk[3] = (c4.z << 14) | c4.w;
        } else {
            #pragma unroll
            for (int u = 0; u < 4; ++u) {
                pv[u] = -1; pk[u] = 0;
                if (f0 + u < Fn) {
                    pv[u] = facts[3 * (f0 + u)];
                    pk[u] = (facts[3 * (f0 + u) + 1] << 14) | facts[3 * (f0 + u) + 2];
                }
            }
        }
        #pragma unroll
        for (int u = 0; u < 4; ++u) {
            if (pv[u] >= 0) {
                const int j0 = qstart[pv[u]], j1 = j0 + qcnt[pv[u]];
                for (int j = j0; j < j1; ++j) {
                    const int4 qq = qlist[j];
                    if (((pk[u] ^ qq.x) & qq.y) == 0) {
                        const int pos = atomicAdd(&ecnt, 1);
                        if (pos < BCAP) ebuf[pos] = qq.z | (f0 + u);
                    }
                }
            }
        }
        __syncthreads();
        const int n = (ecnt < BCAP) ? ecnt : BCAP;
        if (t == 0) ws[OFF_BCNT + B] = n;
        if (t < n) ws[OFF_BENT + B * BCAP + t] = ebuf[t];
    } else {
        // ================= first-64-per-predicate role =================
        __shared__ int wave_tot[4];
        const int p = blockIdx.x - NBLK + 1;       // predicate 1..50

        int total = 0;
        for (int base = 0; base < Fn && total < KF; base += 1024) {
            const int f0 = base + t * 4;
            unsigned mbits = 0;
            if (f0 + 3 < Fn) {
                const int4* p4 = (const int4*)(facts + 3 * f0);
                int4 a = p4[0], b4 = p4[1], c4 = p4[2];
                if (a.x  == p) mbits |= 1u;
                if (a.w  == p) mbits |= 2u;
                if (b4.z == p) mbits |= 4u;
                if (c4.y == p) mbits |= 8u;
            } else {
                #pragma unroll
                for (int u = 0; u < 4; ++u)
                    if (f0 + u < Fn && facts[3 * (f0 + u)] == p) mbits |= (1u << u);
            }
            const int c4n = __popc(mbits);

            int v = c4n;
            #pragma unroll
            for (int off = 1; off < 64; off <<= 1) {
                int n = __shfl_up(v, off, 64);
                if (lane >= off) v += n;
            }
            if (lane == 63) wave_tot[wv] = v;
            __syncthreads();
            int excl = v - c4n;
            #pragma unroll
            for (int w = 0; w < 4; ++w) if (w < wv) excl += wave_tot[w];
            const int ctot = wave_tot[0] + wave_tot[1] + wave_tot[2] + wave_tot[3];

            int pos = total + excl;
            #pragma unroll
            for (int u = 0; u < 4; ++u) {
                if (mbits & (1u << u)) {
                    if (pos < KF) ws[OFF_PFIRST + p * 64 + pos] = f0 + u;
                    pos++;
                }
            }
            total += ctot;
            __syncthreads();
        }
        if (t == 0) ws[OFF_PN + p] = (total < KF) ? total : KF;
    }
}

// ---------- finalize + select: one block per batch ----------
__global__ __launch_bounds__(256) void finalize_kernel(
    const int* __restrict__ goals, const float* __restrict__ ss,
    const int* __restrict__ facts, const float* __restrict__ fsc,
    const int* __restrict__ heads, const int* __restrict__ bodies,
    const int* __restrict__ rlens, const float* __restrict__ rsc,
    const int* __restrict__ ws, float* __restrict__ outp)
{
    __shared__ int sfx[Sn * 64];        // 16 KB: fact idx per state (sorted later)
    __shared__ int E[1024];             // compacted packed entries (all batches)
    __shared__ int base[256];
    __shared__ int wtot[4];
    __shared__ int lcnt[Sn];            // per-state gather counters
    __shared__ int seg[4][Sn][16];      // rule segments (50 rules/wave)
    __shared__ int segc[4][Sn];
    __shared__ int hds[Rn * 3];
    __shared__ int pref[Sn + 1];
    __shared__ int nfs[Sn], vvf[Sn], qps[Sn];

    const int b = blockIdx.x, t = threadIdx.x;
    const int lane = t & 63, wv = t >> 6;

    for (int k = t; k < Rn * 3; k += 256) hds[k] = heads[k];
    segc[wv][lane] = 0;
    if (t < Sn) lcnt[t] = 0;

    // prefix over the 196 probe-block counts -> entry bases
    const int myc = (t < NBLK) ? ws[OFF_BCNT + t] : 0;
    {
        int incl = myc;
        #pragma unroll
        for (int off = 1; off < 64; off <<= 1) {
            int n = __shfl_up(incl, off, 64);
            if (lane >= off) incl += n;
        }
        if (lane == 63) wtot[wv] = incl;
        __syncthreads();
        int excl = incl - myc;
        #pragma unroll
        for (int w = 0; w < 4; ++w) if (w < wv) excl += wtot[w];
        base[t] = excl;
    }
    __syncthreads();
    const int totalE0 = wtot[0] + wtot[1] + wtot[2] + wtot[3];
    const int totalE = (totalE0 < 1024) ? totalE0 : 1024;

    // compact entries into LDS
    if (t < NBLK) {
        for (int k = 0; k < myc; ++k) {
            const int dst = base[t] + k;
            if (dst < 1024) E[dst] = ws[OFF_BENT + t * BCAP + k];
        }
    }

    // rules: wave wv checks rules [wv*50, wv*50+50) for state s=lane
    {
        const int s = lane;
        const int* q = goals + (b * Sn + s) * (Gn * 3);
        const int qp = q[0], qa0 = q[1], qa1 = q[2];
        const bool v0 = isv(qa0), v1 = isv(qa1);
        const bool active = (qp != PAD);
        int cnt = 0;
        const int r0 = wv * 50;
        for (int r = r0; r < r0 + 50; ++r) {
            const int h0 = hds[3 * r], h1 = hds[3 * r + 1], h2 = hds[3 * r + 2];
            if (active && h0 == qp && (isv(h1) || v0 || qa0 == h1)
                                   && (isv(h2) || v1 || qa1 == h2)) {
                if (cnt < 16) seg[wv][s][cnt] = r;
                cnt++;
            }
        }
        segc[wv][s] = (cnt < 16) ? cnt : 16;
    }
    __syncthreads();

    // cooperative gather: all 256 threads, 1 entry each (order fixed by sort below)
    for (int i = t; i < totalE; i += 256) {
        const int e = E[i];
        const int gs = e >> 18;
        if ((gs >> 6) == b) {
            const int s = gs & 63;
            const int pos = atomicAdd(&lcnt[s], 1);
            if (pos < KF) sfx[s * 64 + pos] = e & 0x3FFFF;
        }
    }
    __syncthreads();

    // per-state fact lists + prefix
    if (t < Sn) {
        const int s = t;
        const int* q = goals + (b * Sn + s) * (Gn * 3);
        const int qp = q[0], qa0 = q[1], qa1 = q[2];
        const bool v0 = isv(qa0), v1 = isv(qa1);
        const bool active = (qp != PAD);
        const bool vv = active && v0 && v1;
        int nf = 0;
        if (vv) {
            nf = ws[OFF_PN + qp];
        } else if (active) {
            nf = (lcnt[s] < KF) ? lcnt[s] : KF;
            // insertion sort ascending (reference order = ascending fact idx)
            for (int a = 1; a < nf; ++a) {
                const int key = sfx[s * 64 + a];
                int m = a - 1;
                while (m >= 0 && sfx[s * 64 + m] > key) {
                    sfx[s * 64 + m + 1] = sfx[s * 64 + m];
                    m--;
                }
                sfx[s * 64 + m + 1] = key;
            }
        }
        nfs[s] = nf;
        vvf[s] = vv ? 1 : 0;
        qps[s] = qp;
        int nr = segc[0][s] + segc[1][s] + segc[2][s] + segc[3][s];
        if (nr > KR) nr = KR;

        int incl = nf + nr;
        #pragma unroll
        for (int off = 1; off < 64; off <<= 1) {
            int n = __shfl_up(incl, off, 64);
            if (t >= off) incl += n;
        }
        pref[s + 1] = incl;
        if (s == 0) pref[0] = 0;
    }
    __syncthreads();
    const int total = pref[Sn];

    // emit goals: 64 slots x 8 positions = 512 items, 2 per thread
    for (int item = t; item < Sn * Gn; item += 256) {
        const int i = item >> 3, g = item & 7;
        int trip[3] = {PAD, PAD, PAD};
        if (i < total) {
            int lo = 0, hi = Sn - 1;
            while (lo < hi) {
                const int mid = (lo + hi) >> 1;
                if (pref[mid + 1] <= i) lo = mid + 1; else hi = mid;
            }
            const int s = lo, j = i - pref[s];
            const int* q = goals + (b * Sn + s) * (Gn * 3);
            const int qa0 = q[1], qa1 = q[2];
            if (j < nfs[s]) {
                const int fi = vvf[s] ? ws[OFF_PFIRST + qps[s] * 64 + j]
                                      : sfx[s * 64 + j];
                const int f1 = facts[3 * fi + 1], f2 = facts[3 * fi + 2];
                if (g >= 1) {
                    #pragma unroll
                    for (int c = 0; c < 3; ++c) {
                        int x = q[g * 3 + c];
                        if (isv(qa0) && x == qa0) x = f1;
                        else if (isv(qa1) && x == qa1) x = f2;
                        trip[c] = x;
                    }
                }
            } else {
                int jr = j - nfs[s];
                int wz = 0;
                while (jr >= segc[wz][s]) { jr -= segc[wz][s]; wz++; }
                const int ri = seg[wz][s][jr];
                const int h1 = hds[3 * ri + 1], h2 = hds[3 * ri + 2];
                const int len = rlens[ri];
                if (g < BMAXn) {
                    if (g < len) {
                        #pragma unroll
                        for (int c = 0; c < 3; ++c) {
                            int x = bodies[(ri * BMAXn + g) * 3 + c];
                            if (isv(h1) && x == h1) x = qa0;
                            if (isv(h2) && x == h2) x = qa1;
                            trip[c] = x;
                        }
                    }
                } else {
                    trip[0] = q[(g - 2) * 3 + 0];
                    trip[1] = q[(g - 2) * 3 + 1];
                    trip[2] = q[(g - 2) * 3 + 2];
                }
            }
        }
        float* o = outp + ((b * Sn + i) * Gn + g) * 3;
        o[0] = (float)trip[0];
        o[1] = (float)trip[1];
        o[2] = (float)trip[2];
    }

    // scores
    if (t < Sn) {
        const int i = t;
        float sc = 0.f;
        if (i < total) {
            int lo = 0, hi = Sn - 1;
            while (lo < hi) {
                const int mid = (lo + hi) >> 1;
                if (pref[mid + 1] <= i) lo = mid + 1; else hi = mid;
            }
            const int s = lo, j = i - pref[s];
            const float stt = ss[b * Sn + s];
            if (j < nfs[s]) {
                const int fi = vvf[s] ? ws[OFF_PFIRST + qps[s] * 64 + j]
                                      : sfx[s * 64 + j];
                sc = stt * fsc[fi];
            } else {
                int jr = j - nfs[s];
                int wz = 0;
                while (jr >= segc[wz][s]) { jr -= segc[wz][s]; wz++; }
                sc = stt * rsc[seg[wz][s][jr]];
            }
        }
        outp[Bn * Sn * Gn * 3 + b * Sn + t] = sc;
    }
}

extern "C" void kernel_launch(void* const* d_in, const int* in_sizes, int n_in,
                              void* d_out, int out_size, void* d_ws, size_t ws_size,
                              hipStream_t stream) {
    const int*   goals  = (const int*)  d_in[0];
    const float* ss     = (const float*)d_in[1];
    const int*   facts  = (const int*)  d_in[2];
    const float* fsc    = (const float*)d_in[3];
    const int*   heads  = (const int*)  d_in[4];
    const int*   bodies = (const int*)  d_in[5];
    const int*   rlens  = (const int*)  d_in[6];
    const float* rsc    = (const float*)d_in[7];
    int*   ws   = (int*)d_ws;
    float* outp = (float*)d_out;

    probe_kernel   <<<NBLK + 50, 256, 0, stream>>>(goals, facts, ws);
    finalize_kernel<<<Bn,        256, 0, stream>>>(goals, ss, facts, fsc, heads,
                                                   bodies, rlens, rsc, ws, outp);
}